// Round 4
// baseline (713.413 us; speedup 1.0000x reference)
//
#include <hip/hip_runtime.h>

#define NN 100000      // nodes
#define NE 1600000     // edges
#define D  64          // feature dim
#define NBK 512        // dst buckets
#define NPB 196        // nodes per bucket (ceil(NN/NBK)); 512*196=100352 >= NN
#define CHUNK 8192     // edges per binning/hist block
#define NCH ((NE + CHUNK - 1) / CHUNK)   // 196 blocks

// ---- workspace (ints): cnt[NBK] | gcursor[NBK] | bins[NE]  (~6.4 MB) ----

__global__ __launch_bounds__(512) void zero_cnt(int* __restrict__ cnt) {
    cnt[threadIdx.x] = 0;
}

// Per-block LDS histogram of dst-buckets, then one global atomic per bucket.
__global__ __launch_bounds__(256) void hist_kernel(const int* __restrict__ ei,
                                                   int* __restrict__ cnt) {
    __shared__ int lc[NBK];
    const int t = threadIdx.x;
    for (int i = t; i < NBK; i += 256) lc[i] = 0;
    __syncthreads();
    const int base = blockIdx.x * CHUNK;
    #pragma unroll 4
    for (int j = 0; j < CHUNK / 256; ++j) {
        int e = base + t + j * 256;
        if (e < NE) atomicAdd(&lc[(unsigned)ei[NE + e] / NPB], 1);
    }
    __syncthreads();
    for (int i = t; i < NBK; i += 256)
        if (lc[i]) atomicAdd(&cnt[i], lc[i]);
}

// Exclusive scan of 512 bucket counts -> gcursor (allocation cursors).
__global__ __launch_bounds__(NBK) void scan_kernel(const int* __restrict__ cnt,
                                                   int* __restrict__ gcursor) {
    __shared__ int tmp[NBK];
    const int t = threadIdx.x;
    int v = cnt[t];
    tmp[t] = v;
    __syncthreads();
    for (int off = 1; off < NBK; off <<= 1) {
        int u = (t >= off) ? tmp[t - off] : 0;
        __syncthreads();
        tmp[t] += u;
        __syncthreads();
    }
    gcursor[t] = tmp[t] - v;   // exclusive prefix
}

// Two-phase partition: count chunk per bucket in LDS, reserve global ranges
// (one atomic per block x bucket), then write packed (loc<<17)|src per edge.
// Writes are runs of ~16 consecutive ints per (block,bucket) -> line-dense.
__global__ __launch_bounds__(256) void bin_kernel(const int* __restrict__ ei,
                                                  int* __restrict__ gcursor,
                                                  int* __restrict__ bins) {
    __shared__ int lc[NBK];
    __shared__ int lbase[NBK];
    const int t = threadIdx.x;
    const int base = blockIdx.x * CHUNK;

    for (int i = t; i < NBK; i += 256) lc[i] = 0;
    __syncthreads();
    #pragma unroll 4
    for (int j = 0; j < CHUNK / 256; ++j) {
        int e = base + t + j * 256;
        if (e < NE) atomicAdd(&lc[(unsigned)ei[NE + e] / NPB], 1);
    }
    __syncthreads();
    for (int i = t; i < NBK; i += 256) {
        int c = lc[i];
        lbase[i] = c ? atomicAdd(&gcursor[i], c) : 0;
        lc[i] = 0;                 // reuse as local offset counter
    }
    __syncthreads();
    #pragma unroll 4
    for (int j = 0; j < CHUNK / 256; ++j) {
        int e = base + t + j * 256;
        if (e < NE) {
            int src = ei[e];
            int dst = ei[NE + e];
            int b   = (unsigned)dst / NPB;
            int loc = dst - b * NPB;            // < 196, fits 8 bits
            int o   = atomicAdd(&lc[b], 1);
            bins[lbase[b] + o] = (loc << 17) | src;   // src < 2^17
        }
    }
}

// One block per bucket: accumulate x[src] rows into 196x64 fp32 LDS via
// ds_add_f32, then write out (1+eps)*x[node] + rows. 16 waves, 4-edge unroll.
__global__ __launch_bounds__(1024) void agg_kernel(const float* __restrict__ x,
                                                   const float* __restrict__ eps,
                                                   const int* __restrict__ gcursor,
                                                   const int* __restrict__ bins,
                                                   float* __restrict__ out) {
    __shared__ float rows[NPB * D];   // 50176 B
    const int b    = blockIdx.x;
    const int t    = threadIdx.x;
    const int lane = t & 63;
    const int w    = t >> 6;          // 16 waves

    for (int i = t; i < NPB * D; i += 1024) rows[i] = 0.0f;
    __syncthreads();

    const int s0 = (b == 0) ? 0 : gcursor[b - 1];
    const int s1 = gcursor[b];
    const int total = s1 - s0;
    const int nq = total >> 2;        // quads of edges

    for (int q = w; q < nq; q += 16) {
        const int e = s0 + q * 4;
        int pk0 = bins[e], pk1 = bins[e + 1], pk2 = bins[e + 2], pk3 = bins[e + 3];
        float v0 = x[(pk0 & 0x1FFFF) * D + lane];
        float v1 = x[(pk1 & 0x1FFFF) * D + lane];
        float v2 = x[(pk2 & 0x1FFFF) * D + lane];
        float v3 = x[(pk3 & 0x1FFFF) * D + lane];
        atomicAdd(&rows[(pk0 >> 17) * D + lane], v0);
        atomicAdd(&rows[(pk1 >> 17) * D + lane], v1);
        atomicAdd(&rows[(pk2 >> 17) * D + lane], v2);
        atomicAdd(&rows[(pk3 >> 17) * D + lane], v3);
    }
    for (int e = s0 + (nq << 2) + w; e < s1; e += 16) {   // remainder
        int pk = bins[e];
        float v = x[(pk & 0x1FFFF) * D + lane];
        atomicAdd(&rows[(pk >> 17) * D + lane], v);
    }
    __syncthreads();

    const float e1 = 1.0f + *eps;
    for (int r = w; r < NPB; r += 16) {
        int node = b * NPB + r;
        if (node < NN)
            out[node * D + lane] = rows[r * D + lane] + e1 * x[node * D + lane];
    }
}

// In-place MLP on d_out: out = relu(h@W1+b1)@W2+b2. Weights in registers,
// h[k] broadcast via v_readlane.
__global__ __launch_bounds__(256) void mlp_kernel(float* __restrict__ h,
                                                  const float* __restrict__ W1,
                                                  const float* __restrict__ b1,
                                                  const float* __restrict__ W2,
                                                  const float* __restrict__ b2) {
    const int lane   = threadIdx.x & 63;
    const int wave   = blockIdx.x * (blockDim.x >> 6) + (threadIdx.x >> 6);
    const int nwaves = gridDim.x * (blockDim.x >> 6);

    float w1[D], w2[D];
    #pragma unroll
    for (int k = 0; k < D; ++k) {
        w1[k] = W1[k * D + lane];
        w2[k] = W2[k * D + lane];
    }
    const float bb1 = b1[lane];
    const float bb2 = b2[lane];

    for (int node = wave; node < NN; node += nwaves) {
        float hv = h[node * D + lane];
        float acc1 = bb1;
        #pragma unroll
        for (int k = 0; k < D; ++k) {
            float s = __int_as_float(__builtin_amdgcn_readlane(__float_as_int(hv), k));
            acc1 = fmaf(s, w1[k], acc1);
        }
        acc1 = fmaxf(acc1, 0.0f);
        float acc2 = bb2;
        #pragma unroll
        for (int k = 0; k < D; ++k) {
            float s = __int_as_float(__builtin_amdgcn_readlane(__float_as_int(acc1), k));
            acc2 = fmaf(s, w2[k], acc2);
        }
        h[node * D + lane] = acc2;
    }
}

extern "C" void kernel_launch(void* const* d_in, const int* in_sizes, int n_in,
                              void* d_out, int out_size, void* d_ws, size_t ws_size,
                              hipStream_t stream) {
    const float* x   = (const float*)d_in[0];
    const int*   ei  = (const int*)d_in[1];
    const float* W1  = (const float*)d_in[2];
    const float* b1  = (const float*)d_in[3];
    const float* W2  = (const float*)d_in[4];
    const float* b2  = (const float*)d_in[5];
    const float* eps = (const float*)d_in[6];
    float*       out = (float*)d_out;

    int* cnt     = (int*)d_ws;
    int* gcursor = cnt + NBK;
    int* bins    = gcursor + NBK;

    zero_cnt<<<1, NBK, 0, stream>>>(cnt);
    hist_kernel<<<NCH, 256, 0, stream>>>(ei, cnt);
    scan_kernel<<<1, NBK, 0, stream>>>(cnt, gcursor);
    bin_kernel<<<NCH, 256, 0, stream>>>(ei, gcursor, bins);
    agg_kernel<<<NBK, 1024, 0, stream>>>(x, eps, gcursor, bins, out);
    mlp_kernel<<<1024, 256, 0, stream>>>(out, W1, b1, W2, b2);
}

// Round 5
// 240.986 us; speedup vs baseline: 2.9604x; 2.9604x over previous
//
#include <hip/hip_runtime.h>

#define NN 100000      // nodes
#define NE 1600000     // edges
#define D  64          // feature dim
#define NBK 512        // dst buckets
#define NPB 196        // nodes per bucket; 512*196 = 100352 >= NN
#define CHUNK 8192     // edges per hist/bin block
#define NCH ((NE + CHUNK - 1) / CHUNK)   // 196 blocks
#define TCAP 4096      // per-bucket tile capacity (mean 3125, sd 56 -> 17 sigma)

// ---- workspace (ints): cnt[NBK] | gcursor[NBK] | bins[NE] ----

__global__ __launch_bounds__(512) void zero_cnt(int* __restrict__ cnt) {
    cnt[threadIdx.x] = 0;
}

// Per-block LDS histogram of dst-buckets, one global atomic per bucket.
__global__ __launch_bounds__(256) void hist_kernel(const int* __restrict__ ei,
                                                   int* __restrict__ cnt) {
    __shared__ int lc[NBK];
    const int t = threadIdx.x;
    for (int i = t; i < NBK; i += 256) lc[i] = 0;
    __syncthreads();
    const int base = blockIdx.x * CHUNK;
    #pragma unroll 4
    for (int j = 0; j < CHUNK / 256; ++j) {
        int e = base + t + j * 256;
        if (e < NE) atomicAdd(&lc[(unsigned)ei[NE + e] / NPB], 1);
    }
    __syncthreads();
    for (int i = t; i < NBK; i += 256)
        if (lc[i]) atomicAdd(&cnt[i], lc[i]);
}

// Exclusive scan of 512 bucket counts -> gcursor (allocation cursors).
__global__ __launch_bounds__(NBK) void scan_kernel(const int* __restrict__ cnt,
                                                   int* __restrict__ gcursor) {
    __shared__ int tmp[NBK];
    const int t = threadIdx.x;
    int v = cnt[t];
    tmp[t] = v;
    __syncthreads();
    for (int off = 1; off < NBK; off <<= 1) {
        int u = (t >= off) ? tmp[t - off] : 0;
        __syncthreads();
        tmp[t] += u;
        __syncthreads();
    }
    gcursor[t] = tmp[t] - v;   // exclusive prefix
}

// Two-phase partition: per-block bucket counts in LDS, one global atomic per
// (block,bucket) to reserve a range, then packed (loc<<17)|src writes in runs
// of ~16 consecutive ints -> line-dense (vs round-3 fill's 105 MB bounce).
__global__ __launch_bounds__(256) void bin_kernel(const int* __restrict__ ei,
                                                  int* __restrict__ gcursor,
                                                  int* __restrict__ bins) {
    __shared__ int lc[NBK];
    __shared__ int lbase[NBK];
    const int t = threadIdx.x;
    const int base = blockIdx.x * CHUNK;

    for (int i = t; i < NBK; i += 256) lc[i] = 0;
    __syncthreads();
    #pragma unroll 4
    for (int j = 0; j < CHUNK / 256; ++j) {
        int e = base + t + j * 256;
        if (e < NE) atomicAdd(&lc[(unsigned)ei[NE + e] / NPB], 1);
    }
    __syncthreads();
    for (int i = t; i < NBK; i += 256) {
        int c = lc[i];
        lbase[i] = c ? atomicAdd(&gcursor[i], c) : 0;
        lc[i] = 0;                 // reuse as local offset counter
    }
    __syncthreads();
    #pragma unroll 4
    for (int j = 0; j < CHUNK / 256; ++j) {
        int e = base + t + j * 256;
        if (e < NE) {
            int src = ei[e];
            int dst = ei[NE + e];
            int b   = (unsigned)dst / NPB;
            int loc = dst - b * NPB;                  // < 196
            int o   = atomicAdd(&lc[b], 1);
            bins[lbase[b] + o] = (loc << 17) | src;   // src < 2^17
        }
    }
}

// One block per bucket: LDS counting-sort of the bucket's packed edges by
// local node id, then REGISTER-accumulating gather per node (round-3 pattern
// — no LDS-atomic accumulation, that was round 4's 538us mistake).
__global__ __launch_bounds__(1024) void agg_kernel(const float* __restrict__ x,
                                                   const float* __restrict__ eps,
                                                   const int* __restrict__ gcursor,
                                                   const int* __restrict__ bins,
                                                   float* __restrict__ out) {
    __shared__ int sorted[TCAP];   // src ids, grouped by local node
    __shared__ int tmp[256];
    __shared__ int off[256];       // off[r] = start of node r in sorted; off[196]=n
    __shared__ int cur[256];
    const int b    = blockIdx.x;
    const int t    = threadIdx.x;
    const int lane = t & 63;
    const int w    = t >> 6;       // 16 waves
    const int s0   = b ? gcursor[b - 1] : 0;
    const int s1   = gcursor[b];
    const float e1 = 1.0f + *eps;
    const int n_total = s1 - s0;

    if (n_total <= TCAP) {
        // ---- common path: single tile ----
        if (t < 256) tmp[t] = 0;
        __syncthreads();
        for (int i = t; i < n_total; i += 1024)
            atomicAdd(&tmp[bins[s0 + i] >> 17], 1);
        __syncthreads();
        int v = (t < 256) ? tmp[t] : 0;
        for (int o = 1; o < 256; o <<= 1) {        // inclusive scan of counts
            int u = (t < 256 && t >= o) ? tmp[t - o] : 0;
            __syncthreads();
            if (t < 256) tmp[t] += u;
            __syncthreads();
        }
        if (t < 256) { off[t] = tmp[t] - v; cur[t] = tmp[t] - v; }
        __syncthreads();
        for (int i = t; i < n_total; i += 1024) {
            int pk  = bins[s0 + i];
            int pos = atomicAdd(&cur[pk >> 17], 1);
            sorted[pos] = pk & 0x1FFFF;
        }
        __syncthreads();
        #pragma unroll
        for (int j = 0; j < 13; ++j) {
            int r = w + 16 * j;                    // strided: waves 0-3 get 13 rows
            if (r < NPB) {
                int node = b * NPB + r;
                if (node < NN) {
                    float a = e1 * x[node * D + lane];
                    int p  = off[r];
                    int pe = (r + 1 < NPB) ? off[r + 1] : n_total;
                    for (; p + 4 <= pe; p += 4) {
                        int i0 = sorted[p],     i1 = sorted[p + 1];
                        int i2 = sorted[p + 2], i3 = sorted[p + 3];
                        float v0 = x[i0 * D + lane];
                        float v1 = x[i1 * D + lane];
                        float v2 = x[i2 * D + lane];
                        float v3 = x[i3 * D + lane];
                        a += (v0 + v1) + (v2 + v3);
                    }
                    for (; p < pe; ++p) a += x[sorted[p] * D + lane];
                    out[node * D + lane] = a;
                }
            }
        }
    } else {
        // ---- fallback (structurally correct; ~never taken at 17 sigma) ----
        for (int j = 0; j < 13; ++j) {
            int r = w + 16 * j;
            int node = b * NPB + r;
            if (r < NPB && node < NN)
                out[node * D + lane] = e1 * x[node * D + lane];
        }
        for (int base = s0; base < s1; base += TCAP) {
            const int n = min(TCAP, s1 - base);
            if (t < 256) tmp[t] = 0;
            __syncthreads();
            for (int i = t; i < n; i += 1024)
                atomicAdd(&tmp[bins[base + i] >> 17], 1);
            __syncthreads();
            int v = (t < 256) ? tmp[t] : 0;
            for (int o = 1; o < 256; o <<= 1) {
                int u = (t < 256 && t >= o) ? tmp[t - o] : 0;
                __syncthreads();
                if (t < 256) tmp[t] += u;
                __syncthreads();
            }
            if (t < 256) { off[t] = tmp[t] - v; cur[t] = tmp[t] - v; }
            __syncthreads();
            for (int i = t; i < n; i += 1024) {
                int pk  = bins[base + i];
                int pos = atomicAdd(&cur[pk >> 17], 1);
                sorted[pos] = pk & 0x1FFFF;
            }
            __syncthreads();
            for (int j = 0; j < 13; ++j) {
                int r = w + 16 * j;
                if (r < NPB) {
                    int node = b * NPB + r;
                    if (node < NN) {
                        float a = out[node * D + lane];   // same wave owns row
                        int p  = off[r];
                        int pe = (r + 1 < NPB) ? off[r + 1] : n;
                        for (; p < pe; ++p) a += x[sorted[p] * D + lane];
                        out[node * D + lane] = a;
                    }
                }
            }
            __syncthreads();
        }
    }
}

// In-place MLP on d_out: out = relu(h@W1+b1)@W2+b2. Weights in registers,
// h[k] broadcast via v_readlane.
__global__ __launch_bounds__(256) void mlp_kernel(float* __restrict__ h,
                                                  const float* __restrict__ W1,
                                                  const float* __restrict__ b1,
                                                  const float* __restrict__ W2,
                                                  const float* __restrict__ b2) {
    const int lane   = threadIdx.x & 63;
    const int wave   = blockIdx.x * (blockDim.x >> 6) + (threadIdx.x >> 6);
    const int nwaves = gridDim.x * (blockDim.x >> 6);

    float w1[D], w2[D];
    #pragma unroll
    for (int k = 0; k < D; ++k) {
        w1[k] = W1[k * D + lane];
        w2[k] = W2[k * D + lane];
    }
    const float bb1 = b1[lane];
    const float bb2 = b2[lane];

    for (int node = wave; node < NN; node += nwaves) {
        float hv = h[node * D + lane];
        float acc1 = bb1;
        #pragma unroll
        for (int k = 0; k < D; ++k) {
            float s = __int_as_float(__builtin_amdgcn_readlane(__float_as_int(hv), k));
            acc1 = fmaf(s, w1[k], acc1);
        }
        acc1 = fmaxf(acc1, 0.0f);
        float acc2 = bb2;
        #pragma unroll
        for (int k = 0; k < D; ++k) {
            float s = __int_as_float(__builtin_amdgcn_readlane(__float_as_int(acc1), k));
            acc2 = fmaf(s, w2[k], acc2);
        }
        h[node * D + lane] = acc2;
    }
}

extern "C" void kernel_launch(void* const* d_in, const int* in_sizes, int n_in,
                              void* d_out, int out_size, void* d_ws, size_t ws_size,
                              hipStream_t stream) {
    const float* x   = (const float*)d_in[0];
    const int*   ei  = (const int*)d_in[1];
    const float* W1  = (const float*)d_in[2];
    const float* b1  = (const float*)d_in[3];
    const float* W2  = (const float*)d_in[4];
    const float* b2  = (const float*)d_in[5];
    const float* eps = (const float*)d_in[6];
    float*       out = (float*)d_out;

    int* cnt     = (int*)d_ws;
    int* gcursor = cnt + NBK;
    int* bins    = gcursor + NBK;

    zero_cnt<<<1, NBK, 0, stream>>>(cnt);
    hist_kernel<<<NCH, 256, 0, stream>>>(ei, cnt);
    scan_kernel<<<1, NBK, 0, stream>>>(cnt, gcursor);
    bin_kernel<<<NCH, 256, 0, stream>>>(ei, gcursor, bins);
    agg_kernel<<<NBK, 1024, 0, stream>>>(x, eps, gcursor, bins, out);
    mlp_kernel<<<1024, 256, 0, stream>>>(out, W1, b1, W2, b2);
}